// Round 5
// baseline (155.806 us; speedup 1.0000x reference)
//
#include <hip/hip_runtime.h>
#include <hip/hip_bf16.h>

// Problem constants (B=4, S=1024, d=512, H=8, hd=64)
#define BB 4
#define SS 1024
#define DD 512
#define HH 8
#define HD 64

typedef __attribute__((ext_vector_type(8))) short bf16x8;
typedef __attribute__((ext_vector_type(4))) float f32x4;
typedef __attribute__((ext_vector_type(16))) float f32x16;

// fp32 -> bf16 round-to-nearest-even (finite inputs)
static __device__ __forceinline__ unsigned short f2b(float f) {
  union { float f; unsigned int u; } c; c.f = f;
  return (unsigned short)((c.u + 0x7fffu + ((c.u >> 16) & 1u)) >> 16);
}

// ---------------------------------------------------------------------------
// Fused prep (one dispatch, 3968 blocks):
//  [0,1024):    x fp32 -> bf16 (2M)
//  [1024,1280): in_proj_w q|k rows -> bf16 (512K)
//  [1280,1408): out_w -> bf16 (256K)
//  [1408,3456): mask bit-pack: 8 fp32 -> 1 byte
//  [3456,3968): V [B,S,H,hd] fp32 -> Vt [B,H,hd,S] bf16
// ---------------------------------------------------------------------------
__global__ __launch_bounds__(256) void prep(
    const float* __restrict__ x, const float* __restrict__ W1,
    const float* __restrict__ Wo, const float* __restrict__ Mmask,
    const float* __restrict__ V, unsigned short* __restrict__ xb,
    unsigned short* __restrict__ W1b, unsigned short* __restrict__ Wob,
    unsigned char* __restrict__ Mpack, unsigned short* __restrict__ Vt) {
  __shared__ float Ls[64][65];
  const int bid = blockIdx.x;
  const int tid = threadIdx.x;

  if (bid < 1408) {
    const float* src; unsigned short* dst; size_t off;
    if (bid < 1024) { src = x;  dst = xb;  off = ((size_t)bid * 256 + tid) * 8; }
    else if (bid < 1280) { src = W1; dst = W1b; off = ((size_t)(bid - 1024) * 256 + tid) * 8; }
    else { src = Wo; dst = Wob; off = ((size_t)(bid - 1280) * 256 + tid) * 8; }
    const float4 a = *(const float4*)(src + off);
    const float4 b = *(const float4*)(src + off + 4);
    union { unsigned short s[8]; uint4 v; } o;
    o.s[0] = f2b(a.x); o.s[1] = f2b(a.y); o.s[2] = f2b(a.z); o.s[3] = f2b(a.w);
    o.s[4] = f2b(b.x); o.s[5] = f2b(b.y); o.s[6] = f2b(b.z); o.s[7] = f2b(b.w);
    *(uint4*)(dst + off) = o.v;
  } else if (bid < 3456) {
    const size_t g = (size_t)(bid - 1408) * 256 + tid;
    const float4 a = *(const float4*)(Mmask + g * 8);
    const float4 b = *(const float4*)(Mmask + g * 8 + 4);
    unsigned v = 0;
    v |= (a.x > 0.5f) ? 1u : 0u;   v |= (a.y > 0.5f) ? 2u : 0u;
    v |= (a.z > 0.5f) ? 4u : 0u;   v |= (a.w > 0.5f) ? 8u : 0u;
    v |= (b.x > 0.5f) ? 16u : 0u;  v |= (b.y > 0.5f) ? 32u : 0u;
    v |= (b.z > 0.5f) ? 64u : 0u;  v |= (b.w > 0.5f) ? 128u : 0u;
    Mpack[g] = (unsigned char)v;
  } else {
    const int id = bid - 3456;
    const int s0 = (id & 15) * 64, h = (id >> 4) & 7, b = id >> 7;
    {
      const int r = tid >> 2, cs = (tid & 3) * 16;
      const float* src = V + ((size_t)((b * SS + s0 + r) * HH) + h) * HD + cs;
#pragma unroll
      for (int j = 0; j < 4; j++) {
        const float4 v = *(const float4*)(src + j * 4);
        Ls[r][cs + j * 4 + 0] = v.x; Ls[r][cs + j * 4 + 1] = v.y;
        Ls[r][cs + j * 4 + 2] = v.z; Ls[r][cs + j * 4 + 3] = v.w;
      }
    }
    __syncthreads();
    {
      const int d = tid >> 2, ss = (tid & 3) * 16;
      union { unsigned short s[16]; uint4 v[2]; } o;
#pragma unroll
      for (int j = 0; j < 16; j++) o.s[j] = f2b(Ls[ss + j][d]);
      unsigned short* dst =
          Vt + ((size_t)((b * HH + h) * HD + d)) * SS + s0 + ss;
      *(uint4*)dst = o.v[0];
      *(uint4*)(dst + 8) = o.v[1];
    }
  }
}

// ---------------------------------------------------------------------------
// GEMM1: qkb[4096,1024](bf16) = xb(bf16) @ W1b(bf16)^T + bias  (unchanged)
// ---------------------------------------------------------------------------
__global__ __launch_bounds__(256) void gemm_qk(
    const unsigned short* __restrict__ xb, const unsigned short* __restrict__ W1b,
    const float* __restrict__ bias, unsigned short* __restrict__ qkb) {
  __shared__ unsigned short As[128][40];
  __shared__ unsigned short Bs[64][40];
  const int tid = threadIdx.x;
  const int lane = tid & 63, wave = tid >> 6;
  const int l16 = lane & 15, quad = lane >> 4;
  const int row0 = blockIdx.y * 128, col0 = blockIdx.x * 64;

  f32x4 acc[2][4];
#pragma unroll
  for (int i = 0; i < 2; i++)
#pragma unroll
    for (int j = 0; j < 4; j++) acc[i][j] = (f32x4){0.f, 0.f, 0.f, 0.f};

  const int ra = tid >> 1, csa = (tid & 1) * 16;
  const int rb = tid >> 2, csb = (tid & 3) * 8;
  const unsigned short* ap = xb + (size_t)(row0 + ra) * DD + csa;
  const unsigned short* bp = W1b + (size_t)(col0 + rb) * DD + csb;

  uint4 pa0 = *(const uint4*)ap, pa1 = *(const uint4*)(ap + 8);
  uint4 pb = *(const uint4*)bp;

  for (int k0 = 0; k0 < DD; k0 += 32) {
    __syncthreads();
    *(uint4*)&As[ra][csa] = pa0;
    *(uint4*)&As[ra][csa + 8] = pa1;
    *(uint4*)&Bs[rb][csb] = pb;
    __syncthreads();
    if (k0 + 32 < DD) {  // prefetch next slab; vmcnt waits land next iter
      pa0 = *(const uint4*)(ap + k0 + 32);
      pa1 = *(const uint4*)(ap + k0 + 40);
      pb = *(const uint4*)(bp + k0 + 32);
    }

    const bf16x8 a0 = *(const bf16x8*)&As[wave * 32 + l16][quad * 8];
    const bf16x8 a1 = *(const bf16x8*)&As[wave * 32 + 16 + l16][quad * 8];
#pragma unroll
    for (int nt = 0; nt < 4; nt++) {
      const bf16x8 bb = *(const bf16x8*)&Bs[nt * 16 + l16][quad * 8];
      acc[0][nt] = __builtin_amdgcn_mfma_f32_16x16x32_bf16(a0, bb, acc[0][nt], 0, 0, 0);
      acc[1][nt] = __builtin_amdgcn_mfma_f32_16x16x32_bf16(a1, bb, acc[1][nt], 0, 0, 0);
    }
  }

#pragma unroll
  for (int nt = 0; nt < 4; nt++) {
    const int col = col0 + nt * 16 + l16;
    const float bv = bias[col];
    const float scale = (col < DD) ? 0.125f : 1.0f;
#pragma unroll
    for (int mi = 0; mi < 2; mi++)
#pragma unroll
      for (int reg = 0; reg < 4; reg++) {
        const int row = row0 + wave * 32 + mi * 16 + quad * 4 + reg;
        qkb[(size_t)row * 1024 + col] = f2b((acc[mi][nt][reg] + bv) * scale);
      }
  }
}

// ---------------------------------------------------------------------------
// GEMM3: out[4096,512](fp32) = attnb(bf16) @ Wob(bf16)^T + out_b  (unchanged)
// ---------------------------------------------------------------------------
__global__ __launch_bounds__(256) void gemm_out(
    const unsigned short* __restrict__ Ab, const unsigned short* __restrict__ Wob,
    const float* __restrict__ bias, float* __restrict__ out) {
  __shared__ unsigned short As[64][40];
  __shared__ unsigned short Bs[64][40];
  const int tid = threadIdx.x;
  const int lane = tid & 63, wave = tid >> 6;
  const int l16 = lane & 15, quad = lane >> 4;
  const int row0 = blockIdx.y * 64, col0 = blockIdx.x * 64;

  f32x4 acc[4];
#pragma unroll
  for (int j = 0; j < 4; j++) acc[j] = (f32x4){0.f, 0.f, 0.f, 0.f};

  const int r = tid >> 2, cs = (tid & 3) * 8;
  const unsigned short* ap = Ab + (size_t)(row0 + r) * DD + cs;
  const unsigned short* bp = Wob + (size_t)(col0 + r) * DD + cs;

  uint4 pa = *(const uint4*)ap;
  uint4 pb = *(const uint4*)bp;

  for (int k0 = 0; k0 < DD; k0 += 32) {
    __syncthreads();
    *(uint4*)&As[r][cs] = pa;
    *(uint4*)&Bs[r][cs] = pb;
    __syncthreads();
    if (k0 + 32 < DD) {
      pa = *(const uint4*)(ap + k0 + 32);
      pb = *(const uint4*)(bp + k0 + 32);
    }

    const bf16x8 a0 = *(const bf16x8*)&As[wave * 16 + l16][quad * 8];
#pragma unroll
    for (int nt = 0; nt < 4; nt++) {
      const bf16x8 bb = *(const bf16x8*)&Bs[nt * 16 + l16][quad * 8];
      acc[nt] = __builtin_amdgcn_mfma_f32_16x16x32_bf16(a0, bb, acc[nt], 0, 0, 0);
    }
  }

#pragma unroll
  for (int nt = 0; nt < 4; nt++) {
    const int col = col0 + nt * 16 + l16;
    const float bv = bias[col];
#pragma unroll
    for (int reg = 0; reg < 4; reg++) {
      const int row = row0 + wave * 16 + quad * 4 + reg;
      out[(size_t)row * DD + col] = acc[nt][reg] + bv;
    }
  }
}

// ---------------------------------------------------------------------------
// Fused split-k flash attention (r11): 32x32x16 MFMA + in-register P.
//  - 4 waves / 256 threads; wave = (qb = (wave&1)*32, kh = wave>>1).
//    Wave computes S^T[64s x 32q] for its k-half tile then O[32q x 64d].
//  - Swapped QK^T: D col = q = lane&31 -> each lane owns ONE q-row. P stays
//    in registers; the s-redistribution for PV's A-operand is the hi-bit
//    (lane<32 vs >=32) swap only: 8x __shfl_xor(.,32) per 64-key tile.
//    Layout math: lane(hi) holds s = 32*ssub + 4*hi + 8*j + r; A-frag needs
//    s = 16*ks + 8*hi + 2*w(+1); match => holder hi_M = w>>1,
//    j = 2*(ks&1) + hi_receiver, h2 = w&1.
//  - K/V staged in LDS (r8 skeleton: 2-barrier, register-prefetch); each
//    frag read now feeds 2x FLOP (32x32 vs 16x16) => LDS bytes/work halved.
//  - Epilogue: kh=1 waves dump fp32 O into LDS (reuse Ks), kh=0 waves add,
//    scale by invS[q] = 1/(Sm0+Sm1), write attnb bf16.
//  - q pre-scaled 0.125 in gemm_qk -> exp(a) directly; no max shift,
//    no eps*Z term — same numerics as r8.
// LDS: Ks/Vs 36.9KB + SmS/invS < 1KB -> 2 blocks/CU by grid (512 blocks).
// ---------------------------------------------------------------------------
__global__ __launch_bounds__(256) void flash_attn_fused(
    const unsigned short* __restrict__ qkb, const unsigned short* __restrict__ Vt,
    const unsigned char* __restrict__ Mpack, unsigned short* __restrict__ attnb) {
  __shared__ unsigned short Ks[2][64][72];   // [kh][s][k]; epilogue: fp32 O
  __shared__ unsigned short Vs[2][64][72];   // [kh][d][s]
  __shared__ float SmS[2][64];               // per-half row denominators
  __shared__ float invS[64];                 // combined 1/Sm

  const int tid = threadIdx.x;
  const int lane = tid & 63, wave = tid >> 6;
  const int q31 = lane & 31, hi = lane >> 5;
  const int qb = (wave & 1) * 32, kh = wave >> 1;
  const int q0 = blockIdx.x * 64;
  const int h = blockIdx.y;
  const int b = blockIdx.z;

  // Q B-operand frags: lane(col q=q31, rows k = hi*8+{0..7}) per 16-k chunk.
  // B[k][q] read from Q[q][k] memory => contiguous 16B. One-time global load.
  const unsigned short* qp =
      qkb + (size_t)(b * SS + q0 + qb + q31) * 1024 + h * HD;
  bf16x8 bQ[4];
#pragma unroll
  for (int kc = 0; kc < 4; kc++)
    bQ[kc] = *(const bf16x8*)(qp + kc * 16 + hi * 8);

  // mask bytes for q-row q31 of this wave, kh's 8 k-tiles (8 B/iter)
  const unsigned char* mp =
      Mpack + (size_t)(b * SS + q0 + qb + q31) * 128 + kh * 64;
  uint2 pm = *(const uint2*)mp;

  // per-thread staging source pointers (both halves staged by all threads)
  const int r = tid >> 2, cs = (tid & 3) * 16;
  const unsigned short* kp0 =
      qkb + (size_t)(b * SS + r) * 1024 + DD + h * HD + cs;   // keys [0,512)
  const unsigned short* kp1 = kp0 + (size_t)512 * 1024;       // keys [512,1024)
  const unsigned short* vp0 =
      Vt + ((size_t)((b * HH + h) * HD + r)) * SS + cs;
  const unsigned short* vp1 = vp0 + 512;

  uint4 pk0a = *(const uint4*)kp0, pk0b = *(const uint4*)(kp0 + 8);
  uint4 pk1a = *(const uint4*)kp1, pk1b = *(const uint4*)(kp1 + 8);
  uint4 pv0a = *(const uint4*)vp0, pv0b = *(const uint4*)(vp0 + 8);
  uint4 pv1a = *(const uint4*)vp1, pv1b = *(const uint4*)(vp1 + 8);

  float Smp = 0.f;
  f32x16 O[2];
#pragma unroll
  for (int ds = 0; ds < 2; ds++)
#pragma unroll
    for (int j = 0; j < 16; j++) O[ds][j] = 0.f;

  for (int i = 0; i < 8; i++) {
    __syncthreads();  // prior iter's Ks/Vs frag reads complete
    *(uint4*)&Ks[0][r][cs] = pk0a;
    *(uint4*)&Ks[0][r][cs + 8] = pk0b;
    *(uint4*)&Ks[1][r][cs] = pk1a;
    *(uint4*)&Ks[1][r][cs + 8] = pk1b;
    *(uint4*)&Vs[0][r][cs] = pv0a;
    *(uint4*)&Vs[0][r][cs + 8] = pv0b;
    *(uint4*)&Vs[1][r][cs] = pv1a;
    *(uint4*)&Vs[1][r][cs + 8] = pv1b;
    __syncthreads();

    const uint2 pm_cur = pm;
    if (i < 7) {  // prefetch tile i+1; latency hidden by compute below
      const size_t ko = (size_t)(i + 1) * 64 * 1024;
      pk0a = *(const uint4*)(kp0 + ko);
      pk0b = *(const uint4*)(kp0 + ko + 8);
      pk1a = *(const uint4*)(kp1 + ko);
      pk1b = *(const uint4*)(kp1 + ko + 8);
      pv0a = *(const uint4*)(vp0 + (i + 1) * 64);
      pv0b = *(const uint4*)(vp0 + (i + 1) * 64 + 8);
      pv1a = *(const uint4*)(vp1 + (i + 1) * 64);
      pv1b = *(const uint4*)(vp1 + (i + 1) * 64 + 8);
      pm = *(const uint2*)(mp + (i + 1) * 8);
    }

    // ---- QK^T (swapped): per ssub a 32s x 32q tile; exp+mask; pack bf16 ----
    unsigned Wf[16];  // [ssub*8 + j*2 + h2]
#pragma unroll
    for (int ssub = 0; ssub < 2; ssub++) {
      f32x16 acc;
#pragma unroll
      for (int j = 0; j < 16; j++) acc[j] = 0.f;
#pragma unroll
      for (int kc = 0; kc < 4; kc++) {
        const bf16x8 aK =
            *(const bf16x8*)&Ks[kh][ssub * 32 + q31][kc * 16 + hi * 8];
        acc = __builtin_amdgcn_mfma_f32_32x32x16_bf16(aK, bQ[kc], acc, 0, 0, 0);
      }
      const unsigned msh = (ssub ? pm_cur.y : pm_cur.x) >> (hi * 4);
#pragma unroll
      for (int j = 0; j < 4; j++) {
        float e[4];
#pragma unroll
        for (int rr = 0; rr < 4; rr++) {
          const float ev = __expf(acc[j * 4 + rr]);
          e[rr] = ((msh >> (8 * j + rr)) & 1u) ? ev : 0.f;
          Smp += e[rr];
        }
        Wf[ssub * 8 + j * 2 + 0] =
            (unsigned)f2b(e[0]) | ((unsigned)f2b(e[1]) << 16);
        Wf[ssub * 8 + j * 2 + 1] =
            (unsigned)f2b(e[2]) | ((unsigned)f2b(e[3]) << 16);
      }
    }

    // ---- hi-half exchange: sender hi sends j = 2*kb + (1-hi) ----
    unsigned Rf[8];  // [ssub*4 + kb*2 + h2]
#pragma unroll
    for (int ssub = 0; ssub < 2; ssub++)
#pragma unroll
      for (int kb = 0; kb < 2; kb++)
#pragma unroll
        for (int h2 = 0; h2 < 2; h2++) {
          const unsigned send = hi ? Wf[ssub * 8 + (2 * kb) * 2 + h2]
                                   : Wf[ssub * 8 + (2 * kb + 1) * 2 + h2];
          Rf[ssub * 4 + kb * 2 + h2] =
              (unsigned)__shfl_xor((int)send, 32);
        }

    // ---- PV: O[32q x 32d] per dsub; A=P frags assembled in-register ----
#pragma unroll
    for (int ks = 0; ks < 4; ks++) {
      const int ssub = ks >> 1, kb = ks & 1;
      union { unsigned u[4]; bf16x8 v; } ap;
      ap.u[0] = hi ? Rf[ssub * 4 + kb * 2 + 0] : Wf[ssub * 8 + 4 * kb + 0];
      ap.u[1] = hi ? Rf[ssub * 4 + kb * 2 + 1] : Wf[ssub * 8 + 4 * kb + 1];
      ap.u[2] = hi ? Wf[ssub * 8 + (2 * kb + 1) * 2 + 0]
                   : Rf[ssub * 4 + kb * 2 + 0];
      ap.u[3] = hi ? Wf[ssub * 8 + (2 * kb + 1) * 2 + 1]
                   : Rf[ssub * 4 + kb * 2 + 1];
#pragma unroll
      for (int dsub = 0; dsub < 2; dsub++) {
        const bf16x8 bV =
            *(const bf16x8*)&Vs[kh][dsub * 32 + q31][ks * 16 + hi * 8];
        O[dsub] =
            __builtin_amdgcn_mfma_f32_32x32x16_bf16(ap.v, bV, O[dsub], 0, 0, 0);
      }
    }
  }

  // ---- epilogue: in-block split-k combine ----
  Smp += __shfl_xor(Smp, 32);     // partner hi holds the disjoint s-set
  if (lane < 32) SmS[kh][qb + lane] = Smp;

  __syncthreads();  // drains last Ks/Vs reads; SmS visible
  float* Of = reinterpret_cast<float*>(&Ks[0][0][0]);  // 16 KB <= 18.4 KB
  if (kh == 1) {
#pragma unroll
    for (int dsub = 0; dsub < 2; dsub++)
#pragma unroll
      for (int reg = 0; reg < 16; reg++) {
        const int q = qb + (reg & 3) + 8 * (reg >> 2) + 4 * hi;
        Of[q * 64 + dsub * 32 + q31] = O[dsub][reg];
      }
  }
  if (tid < 64) invS[tid] = 1.0f / (SmS[0][tid] + SmS[1][tid] + 1e-12f);
  __syncthreads();

  if (kh == 0) {
#pragma unroll
    for (int dsub = 0; dsub < 2; dsub++)
#pragma unroll
      for (int reg = 0; reg < 16; reg++) {
        const int q = qb + (reg & 3) + 8 * (reg >> 2) + 4 * hi;
        const float v =
            (O[dsub][reg] + Of[q * 64 + dsub * 32 + q31]) * invS[q];
        attnb[(size_t)(b * SS + q0 + q) * DD + h * HD + dsub * 32 + q31] =
            f2b(v);
      }
  }
}

// ---------------------------------------------------------------------------
extern "C" void kernel_launch(void* const* d_in, const int* in_sizes, int n_in,
                              void* d_out, int out_size, void* d_ws,
                              size_t ws_size, hipStream_t stream) {
  const float* x = (const float*)d_in[0];          // [4,1024,512]
  const float* V = (const float*)d_in[1];          // [4,1024,8,64]
  const float* Mmask = (const float*)d_in[2];      // [4,1024,1024]
  const float* in_proj_w = (const float*)d_in[3];  // [1536,512]
  const float* in_proj_b = (const float*)d_in[4];  // [1536]
  const float* out_w = (const float*)d_in[5];      // [512,512]
  const float* out_b = (const float*)d_in[6];      // [512]
  float* out = (float*)d_out;                      // [4,1024,512]

  unsigned char* ws = (unsigned char*)d_ws;
  unsigned short* qkb   = (unsigned short*)(ws);                     // 8 MB
  unsigned short* xb    = (unsigned short*)(ws + (8ull << 20));      // 4 MB
  unsigned short* W1b   = (unsigned short*)(ws + (12ull << 20));     // 1 MB
  unsigned short* Wob   = (unsigned short*)(ws + (13ull << 20));     // 0.5 MB
  unsigned short* Vt    = (unsigned short*)(ws + (14ull << 20));     // 4 MB
  unsigned short* attnb = (unsigned short*)(ws + (18ull << 20));     // 4 MB
  unsigned char*  Mpack = ws + (38ull << 20) + (256u << 10);         // 512 KB

  prep<<<3968, 256, 0, stream>>>(x, in_proj_w, out_w, Mmask, V,
                                 xb, W1b, Wob, Mpack, Vt);
  gemm_qk<<<dim3(16, 32), 256, 0, stream>>>(xb, W1b, in_proj_b, qkb);
  flash_attn_fused<<<dim3(SS / 64, HH, BB), 256, 0, stream>>>(
      qkb, Vt, Mpack, attnb);
  gemm_out<<<dim3(8, 64), 256, 0, stream>>>(attnb, Wob, out_b, out);
}

// Round 6
// 151.490 us; speedup vs baseline: 1.0285x; 1.0285x over previous
//
#include <hip/hip_runtime.h>
#include <hip/hip_bf16.h>

// Problem constants (B=4, S=1024, d=512, H=8, hd=64)
#define BB 4
#define SS 1024
#define DD 512
#define HH 8
#define HD 64

typedef __attribute__((ext_vector_type(8))) short bf16x8;
typedef __attribute__((ext_vector_type(4))) float f32x4;
typedef __attribute__((ext_vector_type(16))) float f32x16;
typedef __attribute__((ext_vector_type(4))) unsigned int u32x4;

// fp32 -> bf16 round-to-nearest-even (finite inputs)
static __device__ __forceinline__ unsigned short f2b(float f) {
  union { float f; unsigned int u; } c; c.f = f;
  return (unsigned short)((c.u + 0x7fffu + ((c.u >> 16) & 1u)) >> 16);
}

// ---------------------------------------------------------------------------
// Fused prep (one dispatch, 3968 blocks):
//  [0,1024):    x fp32 -> bf16 (2M)
//  [1024,1280): in_proj_w q|k rows -> bf16 (512K)
//  [1280,1408): out_w -> bf16 (256K)
//  [1408,3456): mask bit-pack: 8 fp32 -> 1 byte
//  [3456,3968): V [B,S,H,hd] fp32 -> Vt [B,H,hd,S] bf16
// ---------------------------------------------------------------------------
__global__ __launch_bounds__(256) void prep(
    const float* __restrict__ x, const float* __restrict__ W1,
    const float* __restrict__ Wo, const float* __restrict__ Mmask,
    const float* __restrict__ V, unsigned short* __restrict__ xb,
    unsigned short* __restrict__ W1b, unsigned short* __restrict__ Wob,
    unsigned char* __restrict__ Mpack, unsigned short* __restrict__ Vt) {
  __shared__ float Ls[64][65];
  const int bid = blockIdx.x;
  const int tid = threadIdx.x;

  if (bid < 1408) {
    const float* src; unsigned short* dst; size_t off;
    if (bid < 1024) { src = x;  dst = xb;  off = ((size_t)bid * 256 + tid) * 8; }
    else if (bid < 1280) { src = W1; dst = W1b; off = ((size_t)(bid - 1024) * 256 + tid) * 8; }
    else { src = Wo; dst = Wob; off = ((size_t)(bid - 1280) * 256 + tid) * 8; }
    const float4 a = *(const float4*)(src + off);
    const float4 b = *(const float4*)(src + off + 4);
    union { unsigned short s[8]; uint4 v; } o;
    o.s[0] = f2b(a.x); o.s[1] = f2b(a.y); o.s[2] = f2b(a.z); o.s[3] = f2b(a.w);
    o.s[4] = f2b(b.x); o.s[5] = f2b(b.y); o.s[6] = f2b(b.z); o.s[7] = f2b(b.w);
    *(uint4*)(dst + off) = o.v;
  } else if (bid < 3456) {
    const size_t g = (size_t)(bid - 1408) * 256 + tid;
    const float4 a = *(const float4*)(Mmask + g * 8);
    const float4 b = *(const float4*)(Mmask + g * 8 + 4);
    unsigned v = 0;
    v |= (a.x > 0.5f) ? 1u : 0u;   v |= (a.y > 0.5f) ? 2u : 0u;
    v |= (a.z > 0.5f) ? 4u : 0u;   v |= (a.w > 0.5f) ? 8u : 0u;
    v |= (b.x > 0.5f) ? 16u : 0u;  v |= (b.y > 0.5f) ? 32u : 0u;
    v |= (b.z > 0.5f) ? 64u : 0u;  v |= (b.w > 0.5f) ? 128u : 0u;
    Mpack[g] = (unsigned char)v;
  } else {
    const int id = bid - 3456;
    const int s0 = (id & 15) * 64, h = (id >> 4) & 7, b = id >> 7;
    {
      const int r = tid >> 2, cs = (tid & 3) * 16;
      const float* src = V + ((size_t)((b * SS + s0 + r) * HH) + h) * HD + cs;
#pragma unroll
      for (int j = 0; j < 4; j++) {
        const float4 v = *(const float4*)(src + j * 4);
        Ls[r][cs + j * 4 + 0] = v.x; Ls[r][cs + j * 4 + 1] = v.y;
        Ls[r][cs + j * 4 + 2] = v.z; Ls[r][cs + j * 4 + 3] = v.w;
      }
    }
    __syncthreads();
    {
      const int d = tid >> 2, ss = (tid & 3) * 16;
      union { unsigned short s[16]; uint4 v[2]; } o;
#pragma unroll
      for (int j = 0; j < 16; j++) o.s[j] = f2b(Ls[ss + j][d]);
      unsigned short* dst =
          Vt + ((size_t)((b * HH + h) * HD + d)) * SS + s0 + ss;
      *(uint4*)dst = o.v[0];
      *(uint4*)(dst + 8) = o.v[1];
    }
  }
}

// ---------------------------------------------------------------------------
// GEMM1: qkb[4096,1024](bf16) = xb(bf16) @ W1b(bf16)^T + bias  (unchanged)
// ---------------------------------------------------------------------------
__global__ __launch_bounds__(256) void gemm_qk(
    const unsigned short* __restrict__ xb, const unsigned short* __restrict__ W1b,
    const float* __restrict__ bias, unsigned short* __restrict__ qkb) {
  __shared__ unsigned short As[128][40];
  __shared__ unsigned short Bs[64][40];
  const int tid = threadIdx.x;
  const int lane = tid & 63, wave = tid >> 6;
  const int l16 = lane & 15, quad = lane >> 4;
  const int row0 = blockIdx.y * 128, col0 = blockIdx.x * 64;

  f32x4 acc[2][4];
#pragma unroll
  for (int i = 0; i < 2; i++)
#pragma unroll
    for (int j = 0; j < 4; j++) acc[i][j] = (f32x4){0.f, 0.f, 0.f, 0.f};

  const int ra = tid >> 1, csa = (tid & 1) * 16;
  const int rb = tid >> 2, csb = (tid & 3) * 8;
  const unsigned short* ap = xb + (size_t)(row0 + ra) * DD + csa;
  const unsigned short* bp = W1b + (size_t)(col0 + rb) * DD + csb;

  uint4 pa0 = *(const uint4*)ap, pa1 = *(const uint4*)(ap + 8);
  uint4 pb = *(const uint4*)bp;

  for (int k0 = 0; k0 < DD; k0 += 32) {
    __syncthreads();
    *(uint4*)&As[ra][csa] = pa0;
    *(uint4*)&As[ra][csa + 8] = pa1;
    *(uint4*)&Bs[rb][csb] = pb;
    __syncthreads();
    if (k0 + 32 < DD) {  // prefetch next slab; vmcnt waits land next iter
      pa0 = *(const uint4*)(ap + k0 + 32);
      pa1 = *(const uint4*)(ap + k0 + 40);
      pb = *(const uint4*)(bp + k0 + 32);
    }

    const bf16x8 a0 = *(const bf16x8*)&As[wave * 32 + l16][quad * 8];
    const bf16x8 a1 = *(const bf16x8*)&As[wave * 32 + 16 + l16][quad * 8];
#pragma unroll
    for (int nt = 0; nt < 4; nt++) {
      const bf16x8 bb = *(const bf16x8*)&Bs[nt * 16 + l16][quad * 8];
      acc[0][nt] = __builtin_amdgcn_mfma_f32_16x16x32_bf16(a0, bb, acc[0][nt], 0, 0, 0);
      acc[1][nt] = __builtin_amdgcn_mfma_f32_16x16x32_bf16(a1, bb, acc[1][nt], 0, 0, 0);
    }
  }

#pragma unroll
  for (int nt = 0; nt < 4; nt++) {
    const int col = col0 + nt * 16 + l16;
    const float bv = bias[col];
    const float scale = (col < DD) ? 0.125f : 1.0f;
#pragma unroll
    for (int mi = 0; mi < 2; mi++)
#pragma unroll
      for (int reg = 0; reg < 4; reg++) {
        const int row = row0 + wave * 32 + mi * 16 + quad * 4 + reg;
        qkb[(size_t)row * 1024 + col] = f2b((acc[mi][nt][reg] + bv) * scale);
      }
  }
}

// ---------------------------------------------------------------------------
// GEMM3: out[4096,512](fp32) = attnb(bf16) @ Wob(bf16)^T + out_b  (unchanged)
// ---------------------------------------------------------------------------
__global__ __launch_bounds__(256) void gemm_out(
    const unsigned short* __restrict__ Ab, const unsigned short* __restrict__ Wob,
    const float* __restrict__ bias, float* __restrict__ out) {
  __shared__ unsigned short As[64][40];
  __shared__ unsigned short Bs[64][40];
  const int tid = threadIdx.x;
  const int lane = tid & 63, wave = tid >> 6;
  const int l16 = lane & 15, quad = lane >> 4;
  const int row0 = blockIdx.y * 64, col0 = blockIdx.x * 64;

  f32x4 acc[4];
#pragma unroll
  for (int j = 0; j < 4; j++) acc[j] = (f32x4){0.f, 0.f, 0.f, 0.f};

  const int r = tid >> 2, cs = (tid & 3) * 8;
  const unsigned short* ap = Ab + (size_t)(row0 + r) * DD + cs;
  const unsigned short* bp = Wob + (size_t)(col0 + r) * DD + cs;

  uint4 pa = *(const uint4*)ap;
  uint4 pb = *(const uint4*)bp;

  for (int k0 = 0; k0 < DD; k0 += 32) {
    __syncthreads();
    *(uint4*)&As[r][cs] = pa;
    *(uint4*)&Bs[r][cs] = pb;
    __syncthreads();
    if (k0 + 32 < DD) {
      pa = *(const uint4*)(ap + k0 + 32);
      pb = *(const uint4*)(bp + k0 + 32);
    }

    const bf16x8 a0 = *(const bf16x8*)&As[wave * 16 + l16][quad * 8];
#pragma unroll
    for (int nt = 0; nt < 4; nt++) {
      const bf16x8 bb = *(const bf16x8*)&Bs[nt * 16 + l16][quad * 8];
      acc[nt] = __builtin_amdgcn_mfma_f32_16x16x32_bf16(a0, bb, acc[nt], 0, 0, 0);
    }
  }

#pragma unroll
  for (int nt = 0; nt < 4; nt++) {
    const int col = col0 + nt * 16 + l16;
    const float bv = bias[col];
#pragma unroll
    for (int reg = 0; reg < 4; reg++) {
      const int row = row0 + wave * 16 + quad * 4 + reg;
      out[(size_t)row * DD + col] = acc[nt][reg] + bv;
    }
  }
}

// ---------------------------------------------------------------------------
// Fused split-k flash attention (r12): r11 structure (32x32x16 MFMA,
// in-register P, swapped QK^T) with the register-allocation fix:
//  - __launch_bounds__(256, 2): 2 waves/EU -> 256-VGPR budget. r11's
//    implicit budget was 88 VGPR -> ~60 regs spilled to scratch (64 MB
//    of scratch WRITE_SIZE per dispatch, MfmaUtil < 7%).
//  - P-fragment assembly via ext-vector + __builtin_bit_cast (no union,
//    no chance of an alloca round-trip).
// Structure notes (unchanged from r11, correctness-verified):
//  - 4 waves; wave = (qb = (wave&1)*32, kh = wave>>1). Swapped QK^T:
//    D col = q = lane&31 -> lane owns one q-row; P redistribution for PV
//    is only the hi-bit swap: 8x __shfl_xor(.,32) per 64-key tile.
//  - K/V staged in LDS (2-barrier, register-prefetch); 32x32 MFMA makes
//    each frag read feed 2x FLOP vs 16x16.
//  - Epilogue: kh=1 dumps fp32 O into LDS (reuse Ks), kh=0 combines,
//    scales by 1/(Sm0+Sm1), writes attnb bf16.
// ---------------------------------------------------------------------------
__global__ __launch_bounds__(256, 2) void flash_attn_fused(
    const unsigned short* __restrict__ qkb, const unsigned short* __restrict__ Vt,
    const unsigned char* __restrict__ Mpack, unsigned short* __restrict__ attnb) {
  __shared__ unsigned short Ks[2][64][72];   // [kh][s][k]; epilogue: fp32 O
  __shared__ unsigned short Vs[2][64][72];   // [kh][d][s]
  __shared__ float SmS[2][64];               // per-half row denominators
  __shared__ float invS[64];                 // combined 1/Sm

  const int tid = threadIdx.x;
  const int lane = tid & 63, wave = tid >> 6;
  const int q31 = lane & 31, hi = lane >> 5;
  const int qb = (wave & 1) * 32, kh = wave >> 1;
  const int q0 = blockIdx.x * 64;
  const int h = blockIdx.y;
  const int b = blockIdx.z;

  // Q B-operand frags: lane(col q=q31, rows k = hi*8+{0..7}) per 16-k chunk.
  const unsigned short* qp =
      qkb + (size_t)(b * SS + q0 + qb + q31) * 1024 + h * HD;
  bf16x8 bQ[4];
#pragma unroll
  for (int kc = 0; kc < 4; kc++)
    bQ[kc] = *(const bf16x8*)(qp + kc * 16 + hi * 8);

  // mask bytes for q-row q31 of this wave, kh's 8 k-tiles (8 B/iter)
  const unsigned char* mp =
      Mpack + (size_t)(b * SS + q0 + qb + q31) * 128 + kh * 64;
  uint2 pm = *(const uint2*)mp;

  // per-thread staging source pointers (both halves staged by all threads)
  const int r = tid >> 2, cs = (tid & 3) * 16;
  const unsigned short* kp0 =
      qkb + (size_t)(b * SS + r) * 1024 + DD + h * HD + cs;   // keys [0,512)
  const unsigned short* kp1 = kp0 + (size_t)512 * 1024;       // keys [512,1024)
  const unsigned short* vp0 =
      Vt + ((size_t)((b * HH + h) * HD + r)) * SS + cs;
  const unsigned short* vp1 = vp0 + 512;

  uint4 pk0a = *(const uint4*)kp0, pk0b = *(const uint4*)(kp0 + 8);
  uint4 pk1a = *(const uint4*)kp1, pk1b = *(const uint4*)(kp1 + 8);
  uint4 pv0a = *(const uint4*)vp0, pv0b = *(const uint4*)(vp0 + 8);
  uint4 pv1a = *(const uint4*)vp1, pv1b = *(const uint4*)(vp1 + 8);

  float Smp = 0.f;
  f32x16 O[2];
#pragma unroll
  for (int ds = 0; ds < 2; ds++)
#pragma unroll
    for (int j = 0; j < 16; j++) O[ds][j] = 0.f;

  for (int i = 0; i < 8; i++) {
    __syncthreads();  // prior iter's Ks/Vs frag reads complete
    *(uint4*)&Ks[0][r][cs] = pk0a;
    *(uint4*)&Ks[0][r][cs + 8] = pk0b;
    *(uint4*)&Ks[1][r][cs] = pk1a;
    *(uint4*)&Ks[1][r][cs + 8] = pk1b;
    *(uint4*)&Vs[0][r][cs] = pv0a;
    *(uint4*)&Vs[0][r][cs + 8] = pv0b;
    *(uint4*)&Vs[1][r][cs] = pv1a;
    *(uint4*)&Vs[1][r][cs + 8] = pv1b;
    __syncthreads();

    const uint2 pm_cur = pm;
    if (i < 7) {  // prefetch tile i+1; latency hidden by compute below
      const size_t ko = (size_t)(i + 1) * 64 * 1024;
      pk0a = *(const uint4*)(kp0 + ko);
      pk0b = *(const uint4*)(kp0 + ko + 8);
      pk1a = *(const uint4*)(kp1 + ko);
      pk1b = *(const uint4*)(kp1 + ko + 8);
      pv0a = *(const uint4*)(vp0 + (i + 1) * 64);
      pv0b = *(const uint4*)(vp0 + (i + 1) * 64 + 8);
      pv1a = *(const uint4*)(vp1 + (i + 1) * 64);
      pv1b = *(const uint4*)(vp1 + (i + 1) * 64 + 8);
      pm = *(const uint2*)(mp + (i + 1) * 8);
    }

    // ---- QK^T (swapped): per ssub a 32s x 32q tile; exp+mask; pack bf16 ----
    unsigned Wf[16];  // [ssub*8 + j*2 + h2]
#pragma unroll
    for (int ssub = 0; ssub < 2; ssub++) {
      f32x16 acc;
#pragma unroll
      for (int j = 0; j < 16; j++) acc[j] = 0.f;
#pragma unroll
      for (int kc = 0; kc < 4; kc++) {
        const bf16x8 aK =
            *(const bf16x8*)&Ks[kh][ssub * 32 + q31][kc * 16 + hi * 8];
        acc = __builtin_amdgcn_mfma_f32_32x32x16_bf16(aK, bQ[kc], acc, 0, 0, 0);
      }
      const unsigned msh = (ssub ? pm_cur.y : pm_cur.x) >> (hi * 4);
#pragma unroll
      for (int j = 0; j < 4; j++) {
        float e[4];
#pragma unroll
        for (int rr = 0; rr < 4; rr++) {
          const float ev = __expf(acc[j * 4 + rr]);
          e[rr] = ((msh >> (8 * j + rr)) & 1u) ? ev : 0.f;
          Smp += e[rr];
        }
        Wf[ssub * 8 + j * 2 + 0] =
            (unsigned)f2b(e[0]) | ((unsigned)f2b(e[1]) << 16);
        Wf[ssub * 8 + j * 2 + 1] =
            (unsigned)f2b(e[2]) | ((unsigned)f2b(e[3]) << 16);
      }
    }

    // ---- hi-half exchange: sender hi sends j = 2*kb + (1-hi) ----
    unsigned Rf[8];  // [ssub*4 + kb*2 + h2]
#pragma unroll
    for (int ssub = 0; ssub < 2; ssub++)
#pragma unroll
      for (int kb = 0; kb < 2; kb++)
#pragma unroll
        for (int h2 = 0; h2 < 2; h2++) {
          const unsigned send = hi ? Wf[ssub * 8 + (2 * kb) * 2 + h2]
                                   : Wf[ssub * 8 + (2 * kb + 1) * 2 + h2];
          Rf[ssub * 4 + kb * 2 + h2] =
              (unsigned)__shfl_xor((int)send, 32);
        }

    // ---- PV: O[32q x 32d] per dsub; A=P frags assembled in-register ----
#pragma unroll
    for (int ks = 0; ks < 4; ks++) {
      const int ssub = ks >> 1, kb = ks & 1;
      u32x4 t;
      t.x = hi ? Rf[ssub * 4 + kb * 2 + 0] : Wf[ssub * 8 + 4 * kb + 0];
      t.y = hi ? Rf[ssub * 4 + kb * 2 + 1] : Wf[ssub * 8 + 4 * kb + 1];
      t.z = hi ? Wf[ssub * 8 + (2 * kb + 1) * 2 + 0]
               : Rf[ssub * 4 + kb * 2 + 0];
      t.w = hi ? Wf[ssub * 8 + (2 * kb + 1) * 2 + 1]
               : Rf[ssub * 4 + kb * 2 + 1];
      const bf16x8 apv = __builtin_bit_cast(bf16x8, t);
#pragma unroll
      for (int dsub = 0; dsub < 2; dsub++) {
        const bf16x8 bV =
            *(const bf16x8*)&Vs[kh][dsub * 32 + q31][ks * 16 + hi * 8];
        O[dsub] =
            __builtin_amdgcn_mfma_f32_32x32x16_bf16(apv, bV, O[dsub], 0, 0, 0);
      }
    }
  }

  // ---- epilogue: in-block split-k combine ----
  Smp += __shfl_xor(Smp, 32);     // partner hi holds the disjoint s-set
  if (lane < 32) SmS[kh][qb + lane] = Smp;

  __syncthreads();  // drains last Ks/Vs reads; SmS visible
  float* Of = reinterpret_cast<float*>(&Ks[0][0][0]);  // 16 KB <= 18 KB
  if (kh == 1) {
#pragma unroll
    for (int dsub = 0; dsub < 2; dsub++)
#pragma unroll
      for (int reg = 0; reg < 16; reg++) {
        const int q = qb + (reg & 3) + 8 * (reg >> 2) + 4 * hi;
        Of[q * 64 + dsub * 32 + q31] = O[dsub][reg];
      }
  }
  if (tid < 64) invS[tid] = 1.0f / (SmS[0][tid] + SmS[1][tid] + 1e-12f);
  __syncthreads();

  if (kh == 0) {
#pragma unroll
    for (int dsub = 0; dsub < 2; dsub++)
#pragma unroll
      for (int reg = 0; reg < 16; reg++) {
        const int q = qb + (reg & 3) + 8 * (reg >> 2) + 4 * hi;
        const float v =
            (O[dsub][reg] + Of[q * 64 + dsub * 32 + q31]) * invS[q];
        attnb[(size_t)(b * SS + q0 + q) * DD + h * HD + dsub * 32 + q31] =
            f2b(v);
      }
  }
}

// ---------------------------------------------------------------------------
extern "C" void kernel_launch(void* const* d_in, const int* in_sizes, int n_in,
                              void* d_out, int out_size, void* d_ws,
                              size_t ws_size, hipStream_t stream) {
  const float* x = (const float*)d_in[0];          // [4,1024,512]
  const float* V = (const float*)d_in[1];          // [4,1024,8,64]
  const float* Mmask = (const float*)d_in[2];      // [4,1024,1024]
  const float* in_proj_w = (const float*)d_in[3];  // [1536,512]
  const float* in_proj_b = (const float*)d_in[4];  // [1536]
  const float* out_w = (const float*)d_in[5];      // [512,512]
  const float* out_b = (const float*)d_in[6];      // [512]
  float* out = (float*)d_out;                      // [4,1024,512]

  unsigned char* ws = (unsigned char*)d_ws;
  unsigned short* qkb   = (unsigned short*)(ws);                     // 8 MB
  unsigned short* xb    = (unsigned short*)(ws + (8ull << 20));      // 4 MB
  unsigned short* W1b   = (unsigned short*)(ws + (12ull << 20));     // 1 MB
  unsigned short* Wob   = (unsigned short*)(ws + (13ull << 20));     // 0.5 MB
  unsigned short* Vt    = (unsigned short*)(ws + (14ull << 20));     // 4 MB
  unsigned short* attnb = (unsigned short*)(ws + (18ull << 20));     // 4 MB
  unsigned char*  Mpack = ws + (38ull << 20) + (256u << 10);         // 512 KB

  prep<<<3968, 256, 0, stream>>>(x, in_proj_w, out_w, Mmask, V,
                                 xb, W1b, Wob, Mpack, Vt);
  gemm_qk<<<dim3(16, 32), 256, 0, stream>>>(xb, W1b, in_proj_b, qkb);
  flash_attn_fused<<<dim3(SS / 64, HH, BB), 256, 0, stream>>>(
      qkb, Vt, Mpack, attnb);
  gemm_out<<<dim3(8, 64), 256, 0, stream>>>(attnb, Wob, out_b, out);
}

// Round 7
// 132.750 us; speedup vs baseline: 1.1737x; 1.1412x over previous
//
#include <hip/hip_runtime.h>
#include <hip/hip_bf16.h>

// Problem constants (B=4, S=1024, d=512, H=8, hd=64)
#define BB 4
#define SS 1024
#define DD 512
#define HH 8
#define HD 64

typedef __attribute__((ext_vector_type(8))) short bf16x8;
typedef __attribute__((ext_vector_type(4))) float f32x4;

// fp32 -> bf16 round-to-nearest-even (finite inputs)
static __device__ __forceinline__ unsigned short f2b(float f) {
  union { float f; unsigned int u; } c; c.f = f;
  return (unsigned short)((c.u + 0x7fffu + ((c.u >> 16) & 1u)) >> 16);
}

// ---------------------------------------------------------------------------
// Fused prep (one dispatch, 3968 blocks):
//  [0,1024):    x fp32 -> bf16 (2M)
//  [1024,1280): in_proj_w q|k rows -> bf16 (512K)
//  [1280,1408): out_w -> bf16 (256K)
//  [1408,3456): mask bit-pack: 8 fp32 -> 1 byte
//  [3456,3968): V [B,S,H,hd] fp32 -> Vt [B,H,hd,S] bf16
// ---------------------------------------------------------------------------
__global__ __launch_bounds__(256) void prep(
    const float* __restrict__ x, const float* __restrict__ W1,
    const float* __restrict__ Wo, const float* __restrict__ Mmask,
    const float* __restrict__ V, unsigned short* __restrict__ xb,
    unsigned short* __restrict__ W1b, unsigned short* __restrict__ Wob,
    unsigned char* __restrict__ Mpack, unsigned short* __restrict__ Vt) {
  __shared__ float Ls[64][65];
  const int bid = blockIdx.x;
  const int tid = threadIdx.x;

  if (bid < 1408) {
    const float* src; unsigned short* dst; size_t off;
    if (bid < 1024) { src = x;  dst = xb;  off = ((size_t)bid * 256 + tid) * 8; }
    else if (bid < 1280) { src = W1; dst = W1b; off = ((size_t)(bid - 1024) * 256 + tid) * 8; }
    else { src = Wo; dst = Wob; off = ((size_t)(bid - 1280) * 256 + tid) * 8; }
    const float4 a = *(const float4*)(src + off);
    const float4 b = *(const float4*)(src + off + 4);
    union { unsigned short s[8]; uint4 v; } o;
    o.s[0] = f2b(a.x); o.s[1] = f2b(a.y); o.s[2] = f2b(a.z); o.s[3] = f2b(a.w);
    o.s[4] = f2b(b.x); o.s[5] = f2b(b.y); o.s[6] = f2b(b.z); o.s[7] = f2b(b.w);
    *(uint4*)(dst + off) = o.v;
  } else if (bid < 3456) {
    const size_t g = (size_t)(bid - 1408) * 256 + tid;
    const float4 a = *(const float4*)(Mmask + g * 8);
    const float4 b = *(const float4*)(Mmask + g * 8 + 4);
    unsigned v = 0;
    v |= (a.x > 0.5f) ? 1u : 0u;   v |= (a.y > 0.5f) ? 2u : 0u;
    v |= (a.z > 0.5f) ? 4u : 0u;   v |= (a.w > 0.5f) ? 8u : 0u;
    v |= (b.x > 0.5f) ? 16u : 0u;  v |= (b.y > 0.5f) ? 32u : 0u;
    v |= (b.z > 0.5f) ? 64u : 0u;  v |= (b.w > 0.5f) ? 128u : 0u;
    Mpack[g] = (unsigned char)v;
  } else {
    const int id = bid - 3456;
    const int s0 = (id & 15) * 64, h = (id >> 4) & 7, b = id >> 7;
    {
      const int r = tid >> 2, cs = (tid & 3) * 16;
      const float* src = V + ((size_t)((b * SS + s0 + r) * HH) + h) * HD + cs;
#pragma unroll
      for (int j = 0; j < 4; j++) {
        const float4 v = *(const float4*)(src + j * 4);
        Ls[r][cs + j * 4 + 0] = v.x; Ls[r][cs + j * 4 + 1] = v.y;
        Ls[r][cs + j * 4 + 2] = v.z; Ls[r][cs + j * 4 + 3] = v.w;
      }
    }
    __syncthreads();
    {
      const int d = tid >> 2, ss = (tid & 3) * 16;
      union { unsigned short s[16]; uint4 v[2]; } o;
#pragma unroll
      for (int j = 0; j < 16; j++) o.s[j] = f2b(Ls[ss + j][d]);
      unsigned short* dst =
          Vt + ((size_t)((b * HH + h) * HD + d)) * SS + s0 + ss;
      *(uint4*)dst = o.v[0];
      *(uint4*)(dst + 8) = o.v[1];
    }
  }
}

// ---------------------------------------------------------------------------
// GEMM1: qkb[4096,1024](bf16) = xb(bf16) @ W1b(bf16)^T + bias  (unchanged)
// ---------------------------------------------------------------------------
__global__ __launch_bounds__(256) void gemm_qk(
    const unsigned short* __restrict__ xb, const unsigned short* __restrict__ W1b,
    const float* __restrict__ bias, unsigned short* __restrict__ qkb) {
  __shared__ unsigned short As[128][40];
  __shared__ unsigned short Bs[64][40];
  const int tid = threadIdx.x;
  const int lane = tid & 63, wave = tid >> 6;
  const int l16 = lane & 15, quad = lane >> 4;
  const int row0 = blockIdx.y * 128, col0 = blockIdx.x * 64;

  f32x4 acc[2][4];
#pragma unroll
  for (int i = 0; i < 2; i++)
#pragma unroll
    for (int j = 0; j < 4; j++) acc[i][j] = (f32x4){0.f, 0.f, 0.f, 0.f};

  const int ra = tid >> 1, csa = (tid & 1) * 16;
  const int rb = tid >> 2, csb = (tid & 3) * 8;
  const unsigned short* ap = xb + (size_t)(row0 + ra) * DD + csa;
  const unsigned short* bp = W1b + (size_t)(col0 + rb) * DD + csb;

  uint4 pa0 = *(const uint4*)ap, pa1 = *(const uint4*)(ap + 8);
  uint4 pb = *(const uint4*)bp;

  for (int k0 = 0; k0 < DD; k0 += 32) {
    __syncthreads();
    *(uint4*)&As[ra][csa] = pa0;
    *(uint4*)&As[ra][csa + 8] = pa1;
    *(uint4*)&Bs[rb][csb] = pb;
    __syncthreads();
    if (k0 + 32 < DD) {  // prefetch next slab; vmcnt waits land next iter
      pa0 = *(const uint4*)(ap + k0 + 32);
      pa1 = *(const uint4*)(ap + k0 + 40);
      pb = *(const uint4*)(bp + k0 + 32);
    }

    const bf16x8 a0 = *(const bf16x8*)&As[wave * 32 + l16][quad * 8];
    const bf16x8 a1 = *(const bf16x8*)&As[wave * 32 + 16 + l16][quad * 8];
#pragma unroll
    for (int nt = 0; nt < 4; nt++) {
      const bf16x8 bb = *(const bf16x8*)&Bs[nt * 16 + l16][quad * 8];
      acc[0][nt] = __builtin_amdgcn_mfma_f32_16x16x32_bf16(a0, bb, acc[0][nt], 0, 0, 0);
      acc[1][nt] = __builtin_amdgcn_mfma_f32_16x16x32_bf16(a1, bb, acc[1][nt], 0, 0, 0);
    }
  }

#pragma unroll
  for (int nt = 0; nt < 4; nt++) {
    const int col = col0 + nt * 16 + l16;
    const float bv = bias[col];
    const float scale = (col < DD) ? 0.125f : 1.0f;
#pragma unroll
    for (int mi = 0; mi < 2; mi++)
#pragma unroll
      for (int reg = 0; reg < 4; reg++) {
        const int row = row0 + wave * 32 + mi * 16 + quad * 4 + reg;
        qkb[(size_t)row * 1024 + col] = f2b((acc[mi][nt][reg] + bv) * scale);
      }
  }
}

// ---------------------------------------------------------------------------
// GEMM3: out[4096,512](fp32) = attnb(bf16) @ Wob(bf16)^T + out_b  (unchanged)
// ---------------------------------------------------------------------------
__global__ __launch_bounds__(256) void gemm_out(
    const unsigned short* __restrict__ Ab, const unsigned short* __restrict__ Wob,
    const float* __restrict__ bias, float* __restrict__ out) {
  __shared__ unsigned short As[64][40];
  __shared__ unsigned short Bs[64][40];
  const int tid = threadIdx.x;
  const int lane = tid & 63, wave = tid >> 6;
  const int l16 = lane & 15, quad = lane >> 4;
  const int row0 = blockIdx.y * 64, col0 = blockIdx.x * 64;

  f32x4 acc[4];
#pragma unroll
  for (int j = 0; j < 4; j++) acc[j] = (f32x4){0.f, 0.f, 0.f, 0.f};

  const int r = tid >> 2, cs = (tid & 3) * 8;
  const unsigned short* ap = Ab + (size_t)(row0 + r) * DD + cs;
  const unsigned short* bp = Wob + (size_t)(col0 + r) * DD + cs;

  uint4 pa = *(const uint4*)ap;
  uint4 pb = *(const uint4*)bp;

  for (int k0 = 0; k0 < DD; k0 += 32) {
    __syncthreads();
    *(uint4*)&As[r][cs] = pa;
    *(uint4*)&Bs[r][cs] = pb;
    __syncthreads();
    if (k0 + 32 < DD) {
      pa = *(const uint4*)(ap + k0 + 32);
      pb = *(const uint4*)(bp + k0 + 32);
    }

    const bf16x8 a0 = *(const bf16x8*)&As[wave * 16 + l16][quad * 8];
#pragma unroll
    for (int nt = 0; nt < 4; nt++) {
      const bf16x8 bb = *(const bf16x8*)&Bs[nt * 16 + l16][quad * 8];
      acc[nt] = __builtin_amdgcn_mfma_f32_16x16x32_bf16(a0, bb, acc[nt], 0, 0, 0);
    }
  }

#pragma unroll
  for (int nt = 0; nt < 4; nt++) {
    const int col = col0 + nt * 16 + l16;
    const float bv = bias[col];
#pragma unroll
    for (int reg = 0; reg < 4; reg++) {
      const int row = row0 + wave * 16 + quad * 4 + reg;
      out[(size_t)row * DD + col] = acc[nt][reg] + bv;
    }
  }
}

// ---------------------------------------------------------------------------
// Fused split-k flash attention (r13): r8-verified kernel + XCD-aware block
// swizzle. The r11/r12 profiles showed FETCH ~36-39 MB vs ~12.5 MB unique:
// the 16 q-tile blocks sharing one (b,h) K/V slab (256 KB) were spread
// round-robin over 8 XCD-private L2s, each re-fetching the slab from HBM.
// Flat 512-block grid, decoded so each (b,h) group's 16 blocks land on ONE
// XCD (xcd = g&7 fixed per group; 4 groups x 256 KB = 1 MB per 4 MB L2).
// Kernel body is byte-identical to the r8 structure (verified at 135.5us):
//  - 512 thr / 8 waves; waves 0-3 = k-tiles [0,8), waves 4-7 = [8,16).
//  - K/V both halves staged per iter (register-prefetch, 2 barriers).
//  - P in wave-private LDS rows (QP aliased for sp=0, P2 for sp=1).
//  - Epilogue: in-block split-k combine via LDS, write attnb bf16.
// ---------------------------------------------------------------------------
__global__ __launch_bounds__(512, 4) void flash_attn_fused(
    const unsigned short* __restrict__ qkb, const unsigned short* __restrict__ Vt,
    const unsigned char* __restrict__ Mpack, unsigned short* __restrict__ attnb) {
  __shared__ unsigned short QP[64][72];     // Q staging; then P for sp=0 waves
  __shared__ unsigned short P2[64][72];     // P for sp=1 waves
  __shared__ unsigned short Ks[2][64][72];  // K tiles, both halves; epilogue O
  __shared__ unsigned short Vs[2][64][72];  // [d][s], both halves
  __shared__ float SmS[2][64];              // per-half row denominators

  const int tid = threadIdx.x;
  const int lane = tid & 63, wave = tid >> 6;
  const int l16 = lane & 15, quad = lane >> 4;
  const int wq = wave & 3, sp = wave >> 2;

  // XCD-aware decode: g%8 selects the XCD (round-robin dispatch); keep all
  // 16 q-tiles of a (b,h) group on one XCD. Bijective for 512 blocks.
  const int g = blockIdx.x;
  const int xcd = g & 7, loc = g >> 3;       // loc in [0,64)
  const int gr = xcd + 8 * (loc >> 4);       // (b,h) group in [0,32)
  const int q0 = (loc & 15) * 64;
  const int h = gr & 7;
  const int b = gr >> 3;

  const int r2 = tid >> 3, cs2 = (tid & 7) * 8;  // 512-thread staging

  {  // stage Q tile (all 64 rows; frags read into regs before P aliases it)
    const unsigned short* s = qkb + (size_t)(b * SS + q0 + r2) * 1024 + h * HD + cs2;
    *(uint4*)&QP[r2][cs2] = *(const uint4*)s;
  }

  // mask word pipeline: q = q0 + wq*16 + l16, this half's 8 k-tiles
  const unsigned char* mp =
      Mpack + (size_t)(b * SS + q0 + wq * 16 + l16) * 128 + sp * 64;
  uint2 pm = *(const uint2*)mp;

  __syncthreads();
  const bf16x8 bQ0 = *(const bf16x8*)&QP[wq * 16 + l16][quad * 8];
  const bf16x8 bQ1 = *(const bf16x8*)&QP[wq * 16 + l16][32 + quad * 8];
  unsigned short(*Ps)[72] =
      (unsigned short(*)[72])(sp ? &P2[wq * 16][0] : &QP[wq * 16][0]);

  float Smp = 0.f;
  f32x4 O[4];
#pragma unroll
  for (int i = 0; i < 4; i++) O[i] = (f32x4){0.f, 0.f, 0.f, 0.f};

  // per-thread staging pointers: each thread stages 16 B of K and V per half
  const unsigned short* kp0 =
      qkb + (size_t)(b * SS + r2) * 1024 + DD + h * HD + cs2;          // keys [0,512)
  const unsigned short* kp1 = kp0 + (size_t)512 * 1024;                 // keys [512,1024)
  const unsigned short* vp0 =
      Vt + ((size_t)((b * HH + h) * HD + r2)) * SS + cs2;
  const unsigned short* vp1 = vp0 + 512;

  uint4 pk0 = *(const uint4*)kp0, pk1 = *(const uint4*)kp1;
  uint4 pv0 = *(const uint4*)vp0, pv1 = *(const uint4*)vp1;

#pragma unroll
  for (int i = 0; i < 8; i++) {
    __syncthreads();  // prior iter's Ks/Vs frag reads complete
    *(uint4*)&Ks[0][r2][cs2] = pk0;
    *(uint4*)&Ks[1][r2][cs2] = pk1;
    *(uint4*)&Vs[0][r2][cs2] = pv0;
    *(uint4*)&Vs[1][r2][cs2] = pv1;
    __syncthreads();

    const uint2 pm_cur = pm;
    if (i < 7) {  // prefetch tile i+1; latency hidden by compute below
      pk0 = *(const uint4*)(kp0 + (size_t)(i + 1) * 64 * 1024);
      pk1 = *(const uint4*)(kp1 + (size_t)(i + 1) * 64 * 1024);
      pv0 = *(const uint4*)(vp0 + (i + 1) * 64);
      pv1 = *(const uint4*)(vp1 + (i + 1) * 64);
      pm = *(const uint2*)(mp + (i + 1) * 8);
    }

    // ---- S^T tiles: D[s=quad*4+reg][q=l16]; exp, mask-bit select, P pack ----
#pragma unroll
    for (int t = 0; t < 4; t++) {
      const bf16x8 aK0 = *(const bf16x8*)&Ks[sp][t * 16 + l16][quad * 8];
      const bf16x8 aK1 = *(const bf16x8*)&Ks[sp][t * 16 + l16][32 + quad * 8];
      f32x4 a = (f32x4){0.f, 0.f, 0.f, 0.f};
      a = __builtin_amdgcn_mfma_f32_16x16x32_bf16(aK0, bQ0, a, 0, 0, 0);
      a = __builtin_amdgcn_mfma_f32_16x16x32_bf16(aK1, bQ1, a, 0, 0, 0);
      const unsigned nib =
          ((t < 2 ? pm_cur.x : pm_cur.y) >> ((t & 1) * 16 + quad * 4)) & 0xFu;
      float e0 = __expf(a[0]); e0 = (nib & 1u) ? e0 : 0.f;
      float e1 = __expf(a[1]); e1 = (nib & 2u) ? e1 : 0.f;
      float e2 = __expf(a[2]); e2 = (nib & 4u) ? e2 : 0.f;
      float e3 = __expf(a[3]); e3 = (nib & 8u) ? e3 : 0.f;
      Smp += (e0 + e1) + (e2 + e3);
      uint2 w;
      w.x = (unsigned)f2b(e0) | ((unsigned)f2b(e1) << 16);
      w.y = (unsigned)f2b(e2) | ((unsigned)f2b(e3) << 16);
      *(uint2*)&Ps[l16][t * 16 + quad * 4] = w;  // ds_write_b64, wave-private
    }

    // ---- O += P @ V (wave-private P; in-wave DS ordering suffices) ----
    const bf16x8 aP0 = *(const bf16x8*)&Ps[l16][quad * 8];
    const bf16x8 aP1 = *(const bf16x8*)&Ps[l16][32 + quad * 8];
#pragma unroll
    for (int dt = 0; dt < 4; dt++) {
      const bf16x8 bV0 = *(const bf16x8*)&Vs[sp][dt * 16 + l16][quad * 8];
      const bf16x8 bV1 = *(const bf16x8*)&Vs[sp][dt * 16 + l16][32 + quad * 8];
      O[dt] = __builtin_amdgcn_mfma_f32_16x16x32_bf16(aP0, bV0, O[dt], 0, 0, 0);
      O[dt] = __builtin_amdgcn_mfma_f32_16x16x32_bf16(aP1, bV1, O[dt], 0, 0, 0);
    }
  }

  // ---- epilogue: in-block split-k combine through LDS ----
  Smp += __shfl_xor(Smp, 16);
  Smp += __shfl_xor(Smp, 32);
  if (lane < 16) SmS[sp][wq * 16 + lane] = Smp;

  __syncthreads();  // all Ks reads drained; SmS visible
  float* Of = reinterpret_cast<float*>(&Ks[0][0][0]);  // 16 KB <= sizeof(Ks)
  if (sp == 1) {
#pragma unroll
    for (int dt = 0; dt < 4; dt++)
#pragma unroll
      for (int reg = 0; reg < 4; reg++)
        Of[(wq * 16 + quad * 4 + reg) * 64 + dt * 16 + l16] = O[dt][reg];
  }
  __syncthreads();

  if (sp == 0) {
    float inv[4];
#pragma unroll
    for (int reg = 0; reg < 4; reg++) {
      const int ql = wq * 16 + quad * 4 + reg;
      inv[reg] = 1.0f / (SmS[0][ql] + SmS[1][ql] + 1e-12f);
    }
#pragma unroll
    for (int dt = 0; dt < 4; dt++)
#pragma unroll
      for (int reg = 0; reg < 4; reg++) {
        const int ql = wq * 16 + quad * 4 + reg;
        const float v = (O[dt][reg] + Of[ql * 64 + dt * 16 + l16]) * inv[reg];
        attnb[(size_t)(b * SS + q0 + ql) * DD + h * HD + dt * 16 + l16] = f2b(v);
      }
  }
}

// ---------------------------------------------------------------------------
extern "C" void kernel_launch(void* const* d_in, const int* in_sizes, int n_in,
                              void* d_out, int out_size, void* d_ws,
                              size_t ws_size, hipStream_t stream) {
  const float* x = (const float*)d_in[0];          // [4,1024,512]
  const float* V = (const float*)d_in[1];          // [4,1024,8,64]
  const float* Mmask = (const float*)d_in[2];      // [4,1024,1024]
  const float* in_proj_w = (const float*)d_in[3];  // [1536,512]
  const float* in_proj_b = (const float*)d_in[4];  // [1536]
  const float* out_w = (const float*)d_in[5];      // [512,512]
  const float* out_b = (const float*)d_in[6];      // [512]
  float* out = (float*)d_out;                      // [4,1024,512]

  unsigned char* ws = (unsigned char*)d_ws;
  unsigned short* qkb   = (unsigned short*)(ws);                     // 8 MB
  unsigned short* xb    = (unsigned short*)(ws + (8ull << 20));      // 4 MB
  unsigned short* W1b   = (unsigned short*)(ws + (12ull << 20));     // 1 MB
  unsigned short* Wob   = (unsigned short*)(ws + (13ull << 20));     // 0.5 MB
  unsigned short* Vt    = (unsigned short*)(ws + (14ull << 20));     // 4 MB
  unsigned short* attnb = (unsigned short*)(ws + (18ull << 20));     // 4 MB
  unsigned char*  Mpack = ws + (38ull << 20) + (256u << 10);         // 512 KB

  prep<<<3968, 256, 0, stream>>>(x, in_proj_w, out_w, Mmask, V,
                                 xb, W1b, Wob, Mpack, Vt);
  gemm_qk<<<dim3(16, 32), 256, 0, stream>>>(xb, W1b, in_proj_b, qkb);
  flash_attn_fused<<<512, 512, 0, stream>>>(qkb, Vt, Mpack, attnb);
  gemm_out<<<dim3(8, 64), 256, 0, stream>>>(attnb, Wob, out_b, out);
}

// Round 8
// 130.401 us; speedup vs baseline: 1.1948x; 1.0180x over previous
//
#include <hip/hip_runtime.h>
#include <hip/hip_bf16.h>

// Problem constants (B=4, S=1024, d=512, H=8, hd=64)
#define BB 4
#define SS 1024
#define DD 512
#define HH 8
#define HD 64

typedef __attribute__((ext_vector_type(8))) short bf16x8;
typedef __attribute__((ext_vector_type(4))) float f32x4;

// fp32 -> bf16 round-to-nearest-even (finite inputs)
static __device__ __forceinline__ unsigned short f2b(float f) {
  union { float f; unsigned int u; } c; c.f = f;
  return (unsigned short)((c.u + 0x7fffu + ((c.u >> 16) & 1u)) >> 16);
}

// two fp32 -> packed bf16x2 (RNE, bit-identical to f2b pair) in ONE VALU op
static __device__ __forceinline__ unsigned cvtpk(float lo, float hi) {
  unsigned r;
  asm("v_cvt_pk_bf16_f32 %0, %1, %2" : "=v"(r) : "v"(lo), "v"(hi));
  return r;
}

// ---------------------------------------------------------------------------
// Fused prep (one dispatch, 3968 blocks):
//  [0,1024):    x fp32 -> bf16 (2M)
//  [1024,1280): in_proj_w q|k rows -> bf16 (512K)
//  [1280,1408): out_w -> bf16 (256K)
//  [1408,3456): mask bit-pack: 8 fp32 -> 1 byte
//  [3456,3968): V [B,S,H,hd] fp32 -> Vt [B,H,hd,S] bf16
// ---------------------------------------------------------------------------
__global__ __launch_bounds__(256) void prep(
    const float* __restrict__ x, const float* __restrict__ W1,
    const float* __restrict__ Wo, const float* __restrict__ Mmask,
    const float* __restrict__ V, unsigned short* __restrict__ xb,
    unsigned short* __restrict__ W1b, unsigned short* __restrict__ Wob,
    unsigned char* __restrict__ Mpack, unsigned short* __restrict__ Vt) {
  __shared__ float Ls[64][65];
  const int bid = blockIdx.x;
  const int tid = threadIdx.x;

  if (bid < 1408) {
    const float* src; unsigned short* dst; size_t off;
    if (bid < 1024) { src = x;  dst = xb;  off = ((size_t)bid * 256 + tid) * 8; }
    else if (bid < 1280) { src = W1; dst = W1b; off = ((size_t)(bid - 1024) * 256 + tid) * 8; }
    else { src = Wo; dst = Wob; off = ((size_t)(bid - 1280) * 256 + tid) * 8; }
    const float4 a = *(const float4*)(src + off);
    const float4 b = *(const float4*)(src + off + 4);
    union { unsigned short s[8]; uint4 v; } o;
    o.s[0] = f2b(a.x); o.s[1] = f2b(a.y); o.s[2] = f2b(a.z); o.s[3] = f2b(a.w);
    o.s[4] = f2b(b.x); o.s[5] = f2b(b.y); o.s[6] = f2b(b.z); o.s[7] = f2b(b.w);
    *(uint4*)(dst + off) = o.v;
  } else if (bid < 3456) {
    const size_t g = (size_t)(bid - 1408) * 256 + tid;
    const float4 a = *(const float4*)(Mmask + g * 8);
    const float4 b = *(const float4*)(Mmask + g * 8 + 4);
    unsigned v = 0;
    v |= (a.x > 0.5f) ? 1u : 0u;   v |= (a.y > 0.5f) ? 2u : 0u;
    v |= (a.z > 0.5f) ? 4u : 0u;   v |= (a.w > 0.5f) ? 8u : 0u;
    v |= (b.x > 0.5f) ? 16u : 0u;  v |= (b.y > 0.5f) ? 32u : 0u;
    v |= (b.z > 0.5f) ? 64u : 0u;  v |= (b.w > 0.5f) ? 128u : 0u;
    Mpack[g] = (unsigned char)v;
  } else {
    const int id = bid - 3456;
    const int s0 = (id & 15) * 64, h = (id >> 4) & 7, b = id >> 7;
    {
      const int r = tid >> 2, cs = (tid & 3) * 16;
      const float* src = V + ((size_t)((b * SS + s0 + r) * HH) + h) * HD + cs;
#pragma unroll
      for (int j = 0; j < 4; j++) {
        const float4 v = *(const float4*)(src + j * 4);
        Ls[r][cs + j * 4 + 0] = v.x; Ls[r][cs + j * 4 + 1] = v.y;
        Ls[r][cs + j * 4 + 2] = v.z; Ls[r][cs + j * 4 + 3] = v.w;
      }
    }
    __syncthreads();
    {
      const int d = tid >> 2, ss = (tid & 3) * 16;
      union { unsigned short s[16]; uint4 v[2]; } o;
#pragma unroll
      for (int j = 0; j < 16; j++) o.s[j] = f2b(Ls[ss + j][d]);
      unsigned short* dst =
          Vt + ((size_t)((b * HH + h) * HD + d)) * SS + s0 + ss;
      *(uint4*)dst = o.v[0];
      *(uint4*)(dst + 8) = o.v[1];
    }
  }
}

// ---------------------------------------------------------------------------
// GEMM1: qkb[4096,1024](bf16) = xb(bf16) @ W1b(bf16)^T + bias  (unchanged)
// ---------------------------------------------------------------------------
__global__ __launch_bounds__(256) void gemm_qk(
    const unsigned short* __restrict__ xb, const unsigned short* __restrict__ W1b,
    const float* __restrict__ bias, unsigned short* __restrict__ qkb) {
  __shared__ unsigned short As[128][40];
  __shared__ unsigned short Bs[64][40];
  const int tid = threadIdx.x;
  const int lane = tid & 63, wave = tid >> 6;
  const int l16 = lane & 15, quad = lane >> 4;
  const int row0 = blockIdx.y * 128, col0 = blockIdx.x * 64;

  f32x4 acc[2][4];
#pragma unroll
  for (int i = 0; i < 2; i++)
#pragma unroll
    for (int j = 0; j < 4; j++) acc[i][j] = (f32x4){0.f, 0.f, 0.f, 0.f};

  const int ra = tid >> 1, csa = (tid & 1) * 16;
  const int rb = tid >> 2, csb = (tid & 3) * 8;
  const unsigned short* ap = xb + (size_t)(row0 + ra) * DD + csa;
  const unsigned short* bp = W1b + (size_t)(col0 + rb) * DD + csb;

  uint4 pa0 = *(const uint4*)ap, pa1 = *(const uint4*)(ap + 8);
  uint4 pb = *(const uint4*)bp;

  for (int k0 = 0; k0 < DD; k0 += 32) {
    __syncthreads();
    *(uint4*)&As[ra][csa] = pa0;
    *(uint4*)&As[ra][csa + 8] = pa1;
    *(uint4*)&Bs[rb][csb] = pb;
    __syncthreads();
    if (k0 + 32 < DD) {  // prefetch next slab; vmcnt waits land next iter
      pa0 = *(const uint4*)(ap + k0 + 32);
      pa1 = *(const uint4*)(ap + k0 + 40);
      pb = *(const uint4*)(bp + k0 + 32);
    }

    const bf16x8 a0 = *(const bf16x8*)&As[wave * 32 + l16][quad * 8];
    const bf16x8 a1 = *(const bf16x8*)&As[wave * 32 + 16 + l16][quad * 8];
#pragma unroll
    for (int nt = 0; nt < 4; nt++) {
      const bf16x8 bb = *(const bf16x8*)&Bs[nt * 16 + l16][quad * 8];
      acc[0][nt] = __builtin_amdgcn_mfma_f32_16x16x32_bf16(a0, bb, acc[0][nt], 0, 0, 0);
      acc[1][nt] = __builtin_amdgcn_mfma_f32_16x16x32_bf16(a1, bb, acc[1][nt], 0, 0, 0);
    }
  }

#pragma unroll
  for (int nt = 0; nt < 4; nt++) {
    const int col = col0 + nt * 16 + l16;
    const float bv = bias[col];
    const float scale = (col < DD) ? 0.125f : 1.0f;
#pragma unroll
    for (int mi = 0; mi < 2; mi++)
#pragma unroll
      for (int reg = 0; reg < 4; reg++) {
        const int row = row0 + wave * 32 + mi * 16 + quad * 4 + reg;
        qkb[(size_t)row * 1024 + col] = f2b((acc[mi][nt][reg] + bv) * scale);
      }
  }
}

// ---------------------------------------------------------------------------
// GEMM3: out[4096,512](fp32) = attnb(bf16) @ Wob(bf16)^T + out_b  (unchanged)
// ---------------------------------------------------------------------------
__global__ __launch_bounds__(256) void gemm_out(
    const unsigned short* __restrict__ Ab, const unsigned short* __restrict__ Wob,
    const float* __restrict__ bias, float* __restrict__ out) {
  __shared__ unsigned short As[64][40];
  __shared__ unsigned short Bs[64][40];
  const int tid = threadIdx.x;
  const int lane = tid & 63, wave = tid >> 6;
  const int l16 = lane & 15, quad = lane >> 4;
  const int row0 = blockIdx.y * 64, col0 = blockIdx.x * 64;

  f32x4 acc[4];
#pragma unroll
  for (int j = 0; j < 4; j++) acc[j] = (f32x4){0.f, 0.f, 0.f, 0.f};

  const int r = tid >> 2, cs = (tid & 3) * 8;
  const unsigned short* ap = Ab + (size_t)(row0 + r) * DD + cs;
  const unsigned short* bp = Wob + (size_t)(col0 + r) * DD + cs;

  uint4 pa = *(const uint4*)ap;
  uint4 pb = *(const uint4*)bp;

  for (int k0 = 0; k0 < DD; k0 += 32) {
    __syncthreads();
    *(uint4*)&As[r][cs] = pa;
    *(uint4*)&Bs[r][cs] = pb;
    __syncthreads();
    if (k0 + 32 < DD) {
      pa = *(const uint4*)(ap + k0 + 32);
      pb = *(const uint4*)(bp + k0 + 32);
    }

    const bf16x8 a0 = *(const bf16x8*)&As[wave * 16 + l16][quad * 8];
#pragma unroll
    for (int nt = 0; nt < 4; nt++) {
      const bf16x8 bb = *(const bf16x8*)&Bs[nt * 16 + l16][quad * 8];
      acc[nt] = __builtin_amdgcn_mfma_f32_16x16x32_bf16(a0, bb, acc[nt], 0, 0, 0);
    }
  }

#pragma unroll
  for (int nt = 0; nt < 4; nt++) {
    const int col = col0 + nt * 16 + l16;
    const float bv = bias[col];
#pragma unroll
    for (int reg = 0; reg < 4; reg++) {
      const int row = row0 + wave * 16 + quad * 4 + reg;
      out[(size_t)row * DD + col] = acc[nt][reg] + bv;
    }
  }
}

// ---------------------------------------------------------------------------
// Fused split-k flash attention (r14): r13 kernel (XCD-aware swizzle, r8
// staging skeleton) + v_cvt_pk_bf16_f32 for the P pack. The f2b emulation
// (4 int ops/value) + or/shl packing was ~half the softmax VALU block;
// cvt_pk does 2 values in 1 op with identical RNE rounding (absmax canary
// must stay 0.0004882812).
//  - 512 thr / 8 waves; waves 0-3 = k-tiles [0,8), waves 4-7 = [8,16).
//  - K/V both halves staged per iter (register-prefetch, 2 barriers).
//  - P in wave-private LDS rows (QP aliased for sp=0, P2 for sp=1).
//  - XCD-aware flat grid decode: all 16 q-tiles of a (b,h) group on one XCD.
//  - Epilogue: in-block split-k combine via LDS, write attnb bf16.
// ---------------------------------------------------------------------------
__global__ __launch_bounds__(512, 4) void flash_attn_fused(
    const unsigned short* __restrict__ qkb, const unsigned short* __restrict__ Vt,
    const unsigned char* __restrict__ Mpack, unsigned short* __restrict__ attnb) {
  __shared__ unsigned short QP[64][72];     // Q staging; then P for sp=0 waves
  __shared__ unsigned short P2[64][72];     // P for sp=1 waves
  __shared__ unsigned short Ks[2][64][72];  // K tiles, both halves; epilogue O
  __shared__ unsigned short Vs[2][64][72];  // [d][s], both halves
  __shared__ float SmS[2][64];              // per-half row denominators

  const int tid = threadIdx.x;
  const int lane = tid & 63, wave = tid >> 6;
  const int l16 = lane & 15, quad = lane >> 4;
  const int wq = wave & 3, sp = wave >> 2;

  // XCD-aware decode: g%8 selects the XCD (round-robin dispatch); keep all
  // 16 q-tiles of a (b,h) group on one XCD. Bijective for 512 blocks.
  const int g = blockIdx.x;
  const int xcd = g & 7, loc = g >> 3;       // loc in [0,64)
  const int gr = xcd + 8 * (loc >> 4);       // (b,h) group in [0,32)
  const int q0 = (loc & 15) * 64;
  const int h = gr & 7;
  const int b = gr >> 3;

  const int r2 = tid >> 3, cs2 = (tid & 7) * 8;  // 512-thread staging

  {  // stage Q tile (all 64 rows; frags read into regs before P aliases it)
    const unsigned short* s = qkb + (size_t)(b * SS + q0 + r2) * 1024 + h * HD + cs2;
    *(uint4*)&QP[r2][cs2] = *(const uint4*)s;
  }

  // mask word pipeline: q = q0 + wq*16 + l16, this half's 8 k-tiles
  const unsigned char* mp =
      Mpack + (size_t)(b * SS + q0 + wq * 16 + l16) * 128 + sp * 64;
  uint2 pm = *(const uint2*)mp;

  __syncthreads();
  const bf16x8 bQ0 = *(const bf16x8*)&QP[wq * 16 + l16][quad * 8];
  const bf16x8 bQ1 = *(const bf16x8*)&QP[wq * 16 + l16][32 + quad * 8];
  unsigned short(*Ps)[72] =
      (unsigned short(*)[72])(sp ? &P2[wq * 16][0] : &QP[wq * 16][0]);

  float Smp = 0.f;
  f32x4 O[4];
#pragma unroll
  for (int i = 0; i < 4; i++) O[i] = (f32x4){0.f, 0.f, 0.f, 0.f};

  // per-thread staging pointers: each thread stages 16 B of K and V per half
  const unsigned short* kp0 =
      qkb + (size_t)(b * SS + r2) * 1024 + DD + h * HD + cs2;          // keys [0,512)
  const unsigned short* kp1 = kp0 + (size_t)512 * 1024;                 // keys [512,1024)
  const unsigned short* vp0 =
      Vt + ((size_t)((b * HH + h) * HD + r2)) * SS + cs2;
  const unsigned short* vp1 = vp0 + 512;

  uint4 pk0 = *(const uint4*)kp0, pk1 = *(const uint4*)kp1;
  uint4 pv0 = *(const uint4*)vp0, pv1 = *(const uint4*)vp1;

#pragma unroll
  for (int i = 0; i < 8; i++) {
    __syncthreads();  // prior iter's Ks/Vs frag reads complete
    *(uint4*)&Ks[0][r2][cs2] = pk0;
    *(uint4*)&Ks[1][r2][cs2] = pk1;
    *(uint4*)&Vs[0][r2][cs2] = pv0;
    *(uint4*)&Vs[1][r2][cs2] = pv1;
    __syncthreads();

    const uint2 pm_cur = pm;
    if (i < 7) {  // prefetch tile i+1; latency hidden by compute below
      pk0 = *(const uint4*)(kp0 + (size_t)(i + 1) * 64 * 1024);
      pk1 = *(const uint4*)(kp1 + (size_t)(i + 1) * 64 * 1024);
      pv0 = *(const uint4*)(vp0 + (i + 1) * 64);
      pv1 = *(const uint4*)(vp1 + (i + 1) * 64);
      pm = *(const uint2*)(mp + (i + 1) * 8);
    }

    // ---- S^T tiles: D[s=quad*4+reg][q=l16]; exp, mask-bit select, P pack ----
#pragma unroll
    for (int t = 0; t < 4; t++) {
      const bf16x8 aK0 = *(const bf16x8*)&Ks[sp][t * 16 + l16][quad * 8];
      const bf16x8 aK1 = *(const bf16x8*)&Ks[sp][t * 16 + l16][32 + quad * 8];
      f32x4 a = (f32x4){0.f, 0.f, 0.f, 0.f};
      a = __builtin_amdgcn_mfma_f32_16x16x32_bf16(aK0, bQ0, a, 0, 0, 0);
      a = __builtin_amdgcn_mfma_f32_16x16x32_bf16(aK1, bQ1, a, 0, 0, 0);
      const unsigned nib =
          ((t < 2 ? pm_cur.x : pm_cur.y) >> ((t & 1) * 16 + quad * 4)) & 0xFu;
      float e0 = __expf(a[0]); e0 = (nib & 1u) ? e0 : 0.f;
      float e1 = __expf(a[1]); e1 = (nib & 2u) ? e1 : 0.f;
      float e2 = __expf(a[2]); e2 = (nib & 4u) ? e2 : 0.f;
      float e3 = __expf(a[3]); e3 = (nib & 8u) ? e3 : 0.f;
      Smp += (e0 + e1) + (e2 + e3);
      uint2 w;
      w.x = cvtpk(e0, e1);   // v_cvt_pk_bf16_f32: 2 f32 -> bf16x2, RNE
      w.y = cvtpk(e2, e3);
      *(uint2*)&Ps[l16][t * 16 + quad * 4] = w;  // ds_write_b64, wave-private
    }

    // ---- O += P @ V (wave-private P; in-wave DS ordering suffices) ----
    const bf16x8 aP0 = *(const bf16x8*)&Ps[l16][quad * 8];
    const bf16x8 aP1 = *(const bf16x8*)&Ps[l16][32 + quad * 8];
#pragma unroll
    for (int dt = 0; dt < 4; dt++) {
      const bf16x8 bV0 = *(const bf16x8*)&Vs[sp][dt * 16 + l16][quad * 8];
      const bf16x8 bV1 = *(const bf16x8*)&Vs[sp][dt * 16 + l16][32 + quad * 8];
      O[dt] = __builtin_amdgcn_mfma_f32_16x16x32_bf16(aP0, bV0, O[dt], 0, 0, 0);
      O[dt] = __builtin_amdgcn_mfma_f32_16x16x32_bf16(aP1, bV1, O[dt], 0, 0, 0);
    }
  }

  // ---- epilogue: in-block split-k combine through LDS ----
  Smp += __shfl_xor(Smp, 16);
  Smp += __shfl_xor(Smp, 32);
  if (lane < 16) SmS[sp][wq * 16 + lane] = Smp;

  __syncthreads();  // all Ks reads drained; SmS visible
  float* Of = reinterpret_cast<float*>(&Ks[0][0][0]);  // 16 KB <= sizeof(Ks)
  if (sp == 1) {
#pragma unroll
    for (int dt = 0; dt < 4; dt++)
#pragma unroll
      for (int reg = 0; reg < 4; reg++)
        Of[(wq * 16 + quad * 4 + reg) * 64 + dt * 16 + l16] = O[dt][reg];
  }
  __syncthreads();

  if (sp == 0) {
    float inv[4];
#pragma unroll
    for (int reg = 0; reg < 4; reg++) {
      const int ql = wq * 16 + quad * 4 + reg;
      inv[reg] = 1.0f / (SmS[0][ql] + SmS[1][ql] + 1e-12f);
    }
#pragma unroll
    for (int dt = 0; dt < 4; dt++)
#pragma unroll
      for (int reg = 0; reg < 4; reg++) {
        const int ql = wq * 16 + quad * 4 + reg;
        const float v = (O[dt][reg] + Of[ql * 64 + dt * 16 + l16]) * inv[reg];
        attnb[(size_t)(b * SS + q0 + ql) * DD + h * HD + dt * 16 + l16] = f2b(v);
      }
  }
}

// ---------------------------------------------------------------------------
extern "C" void kernel_launch(void* const* d_in, const int* in_sizes, int n_in,
                              void* d_out, int out_size, void* d_ws,
                              size_t ws_size, hipStream_t stream) {
  const float* x = (const float*)d_in[0];          // [4,1024,512]
  const float* V = (const float*)d_in[1];          // [4,1024,8,64]
  const float* Mmask = (const float*)d_in[2];      // [4,1024,1024]
  const float* in_proj_w = (const float*)d_in[3];  // [1536,512]
  const float* in_proj_b = (const float*)d_in[4];  // [1536]
  const float* out_w = (const float*)d_in[5];      // [512,512]
  const float* out_b = (const float*)d_in[6];      // [512]
  float* out = (float*)d_out;                      // [4,1024,512]

  unsigned char* ws = (unsigned char*)d_ws;
  unsigned short* qkb   = (unsigned short*)(ws);                     // 8 MB
  unsigned short* xb    = (unsigned short*)(ws + (8ull << 20));      // 4 MB
  unsigned short* W1b   = (unsigned short*)(ws + (12ull << 20));     // 1 MB
  unsigned short* Wob   = (unsigned short*)(ws + (13ull << 20));     // 0.5 MB
  unsigned short* Vt    = (unsigned short*)(ws + (14ull << 20));     // 4 MB
  unsigned short* attnb = (unsigned short*)(ws + (18ull << 20));     // 4 MB
  unsigned char*  Mpack = ws + (38ull << 20) + (256u << 10);         // 512 KB

  prep<<<3968, 256, 0, stream>>>(x, in_proj_w, out_w, Mmask, V,
                                 xb, W1b, Wob, Mpack, Vt);
  gemm_qk<<<dim3(16, 32), 256, 0, stream>>>(xb, W1b, in_proj_b, qkb);
  flash_attn_fused<<<512, 512, 0, stream>>>(qkb, Vt, Mpack, attnb);
  gemm_out<<<dim3(8, 64), 256, 0, stream>>>(attnb, Wob, out_b, out);
}